// Round 8
// baseline (3068.763 us; speedup 1.0000x reference)
//
#include <hip/hip_runtime.h>

typedef float f4 __attribute__((ext_vector_type(4)));
typedef float f2 __attribute__((ext_vector_type(2)));

#define B_ 32
#define D_ 128
#define T_ 1024
#define K_ 4096
#define NROWS (B_ * T_)   // 32768
#define BM 64             // rows per workgroup; grid 512
#define LPX 132           // xs row stride (floats)

#define SCHED_FENCE() __builtin_amdgcn_sched_barrier(0)

struct MI { float m; int i; };

// numpy computes t = a*a elementwise, THEN pairwise-sums (no fma fusion).
__device__ __forceinline__ float opaquef(float x) { asm volatile("" : "+v"(x)); return x; }

// numpy pairwise_sum base case for n=128: 8 accumulators,
// ((r0+r1)+(r2+r3))+((r4+r5)+(r6+r7)). Bit-exact replica.
__device__ float np_sumsq128(const float* a) {
  float r[8];
#pragma unroll
  for (int j = 0; j < 8; ++j) r[j] = opaquef(a[j] * a[j]);
#pragma unroll
  for (int i = 8; i < 128; i += 8) {
#pragma unroll
    for (int j = 0; j < 8; ++j) r[j] = r[j] + opaquef(a[i + j] * a[i + j]);
  }
  return ((r[0] + r[1]) + (r[2] + r[3])) + ((r[4] + r[5]) + (r[6] + r[7]));
}

__global__ void wsq_kernel(const float* __restrict__ W, float* __restrict__ wsq) {
  int k = blockIdx.x * blockDim.x + threadIdx.x;
  if (k < K_) wsq[k] = np_sumsq128(W + (size_t)k * D_);
}

// Wtb[(k>>8)][d][k&255] = W[k][d]  — K-blocked transpose, coalesced both sides.
__global__ void transpose_kernel(const float* __restrict__ W, float* __restrict__ Wtb) {
  __shared__ float t[32][33];
  int k0 = blockIdx.x * 32, d0 = blockIdx.y * 32;
  int lx = threadIdx.x & 31, ly = threadIdx.x >> 5;  // 256 thr: ly 0..7
  for (int i = ly; i < 32; i += 8) t[i][lx] = W[(size_t)(k0 + i) * D_ + d0 + lx];
  __syncthreads();
  size_t base = (size_t)(k0 >> 8) * (D_ * 256) + (k0 & 255);
  for (int i = ly; i < 32; i += 8) Wtb[base + (size_t)(d0 + i) * 256 + lx] = t[lx][i];
}

// One d2-block: 8 rows x 4 codes x 2 d's = 64 FMAs. W0 = codes j0..3 at d,
// W1 = at d+1. XA[i] = (x[d], x[d+1]) for row i.
// Chain order per acc: strictly ascending d — bit-exact vs OpenBLAS sgemm.
#define FMA_D2Q(W0, W1, XA)                          \
  do {                                               \
    _Pragma("unroll")                                \
    for (int i_ = 0; i_ < 8; ++i_) {                 \
      float xlo = XA[i_].x;                          \
      float xhi = XA[i_].y;                          \
      _Pragma("unroll")                              \
      for (int j_ = 0; j_ < 4; ++j_) {               \
        float s_ = acc[i_][j_];                      \
        s_ = __fmaf_rn(xlo, W0[j_], s_);             \
        s_ = __fmaf_rn(xhi, W1[j_], s_);             \
        acc[i_][j_] = s_;                            \
      }                                              \
    }                                                \
  } while (0)

#define LDW2(R0, R1)                                 \
  R0 = *(const f4*)(pwb);                            \
  R1 = *(const f4*)(pwb + 1024);                     \
  pwb += 2048;

#define LDX(XBUF, DOFF)                              \
  do {                                               \
    _Pragma("unroll")                                \
    for (int i_ = 0; i_ < 8; ++i_)                   \
      XBUF[i_] = *(const f2*)&xs[ty * 8 + i_][(DOFF)]; \
  } while (0)

__global__ __launch_bounds__(512, 4) void argmin_kernel(
    const float* __restrict__ x, const float* __restrict__ Wtb,
    const float* __restrict__ wsq, int* __restrict__ qout,
    float* __restrict__ out2) {
  __shared__ float xs[BM][LPX];
  __shared__ float xsqs[BM];
  __shared__ MI red[BM][2];
  const int tid = threadIdx.x;
  const int blk = blockIdx.x;
  const int b  = blk >> 4;            // / (T_/BM)
  const int t0 = (blk & 15) * BM;
  const int tx = tid & 31;            // 4 consecutive codes: tx*4..tx*4+3
  const int ty = (tid >> 5) & 7;      // rows ty*8 .. ty*8+7
  const int kh = tid >> 8;            // code half: +kh*128 per 256-tile

  // stage x tile: xs[tt][d] = x[b, d, t0+tt]   (coalesced along t)
  {
    int tt = tid & 63;
    int d0 = (tid >> 6) * 16;
    for (int dd = 0; dd < 16; ++dd) {
      int d = d0 + dd;
      xs[tt][d] = x[((size_t)b * D_ + d) * T_ + t0 + tt];
    }
  }
  __syncthreads();
  if (tid < BM) xsqs[tid] = np_sumsq128(&xs[tid][0]);
  __syncthreads();

  float xq[8];
#pragma unroll
  for (int i = 0; i < 8; ++i) xq[i] = xsqs[ty * 8 + i];

  float m1[8];
  int   i1[8];
#pragma unroll
  for (int i = 0; i < 8; ++i) { m1[i] = 3.4e38f; i1[i] = 0x7fffffff; }

  for (int kt = 0; kt < K_ / 256; ++kt) {
    const char* pwb = (const char*)Wtb + (size_t)kt * (D_ * 256 * 4)
                      + kh * 512 + tx * 16;

    float acc[8][4];
#pragma unroll
    for (int i = 0; i < 8; ++i)
#pragma unroll
      for (int j = 0; j < 4; ++j) acc[i][j] = 0.f;

    // fence-pinned pipeline (r7-proven): 4 W buffers (f4 pairs), 2 x buffers
    f4 a0, a1, b0, b1, c0, c1, e0, e1;
    f2 xa[8], xb[8];
    LDX(xa, 0);
    LDW2(a0, a1)   // d0,d1
    LDW2(b0, b1)   // d2,d3
    LDW2(c0, c1)   // d4,d5

    for (int s = 0; s < 16; ++s) {
      const int d = s * 8;
      LDX(xb, d + 2);
      LDW2(e0, e1)                 // W d+6,7
      SCHED_FENCE();
      FMA_D2Q(a0, a1, xa);         // d, d+1
      SCHED_FENCE();
      LDW2(a0, a1)                 // W d+8,9
      LDX(xa, d + 4);
      SCHED_FENCE();
      FMA_D2Q(b0, b1, xb);         // d+2, d+3
      SCHED_FENCE();
      LDW2(b0, b1)                 // W d+10,11
      LDX(xb, d + 6);
      SCHED_FENCE();
      FMA_D2Q(c0, c1, xa);         // d+4, d+5
      SCHED_FENCE();
      LDW2(c0, c1)                 // W d+12,13 (last iter: slack overread)
      LDX(xa, d + 8);              // x for next iter (last: floats 128..129, in row)
      SCHED_FENCE();
      FMA_D2Q(e0, e1, xb);         // d+6, d+7
      SCHED_FENCE();
    }

    // epilogue: ascending k within thread (j ascending)
    const int kb = kt * 256 + kh * 128 + tx * 4;
    f4 wqa = *(const f4*)&wsq[kb];
#pragma unroll
    for (int j = 0; j < 4; ++j) {
#pragma unroll
      for (int i = 0; i < 8; ++i) {
        float t = __fmaf_rn(-2.0f, acc[i][j], wqa[j]);  // RN(wq - 2*mm)
        float v = __fadd_rn(t, xq[i]);                   // quantizing add
        if (v < m1[i]) { m1[i] = v; i1[i] = kb + j; }    // strict < => first occ.
      }
    }
  }

  // cross-lane reduce over tx (masks <32 stay within the 32-lane half-wave)
#pragma unroll
  for (int i = 0; i < 8; ++i) {
    float m = m1[i];
    int   idx = i1[i];
#pragma unroll
    for (int mask = 16; mask >= 1; mask >>= 1) {
      float mo = __shfl_xor(m, mask);
      int   io = __shfl_xor(idx, mask);
      if (mo < m || (mo == m && io < idx)) { m = mo; idx = io; }
    }
    if (tx == 0) {
      MI t; t.m = m; t.i = idx;
      red[ty * 8 + i][kh] = t;
    }
  }
  __syncthreads();

  // merge the two code-halves: lexicographic (value, index) == np first-occ.
  if (tid < BM) {
    MI A = red[tid][0];
    MI B = red[tid][1];
    int best = (B.m < A.m || (B.m == A.m && B.i < A.i)) ? B.i : A.i;
    int rg = b * T_ + t0 + tid;
    qout[rg] = best;
    out2[rg] = (float)best;
  }
}

// out0[r, d] = W[q[r], d]  — coalesced along d
__global__ void scatter0_kernel(const float* __restrict__ W,
                                const int* __restrict__ q,
                                float* __restrict__ out0) {
  int r = blockIdx.x * 2 + (threadIdx.x >> 7);
  int d = threadIdx.x & 127;
  out0[(size_t)r * D_ + d] = W[(size_t)q[r] * D_ + d];
}

// out1[b, d, t] = W[q[b,t], d]  — coalesced along t
__global__ void scatter1_kernel(const float* __restrict__ W,
                                const int* __restrict__ q,
                                float* __restrict__ out1) {
  int b = blockIdx.x >> 7;
  int d = blockIdx.x & 127;
  for (int t = threadIdx.x; t < T_; t += 256) {
    int k = q[b * T_ + t];
    out1[((size_t)b * D_ + d) * T_ + t] = W[(size_t)k * D_ + d];
  }
}

extern "C" void kernel_launch(void* const* d_in, const int* in_sizes, int n_in,
                              void* d_out, int out_size, void* d_ws, size_t ws_size,
                              hipStream_t stream) {
  const float* x = (const float*)d_in[0];
  const float* W = (const float*)d_in[1];
  float* out  = (float*)d_out;
  float* out0 = out;                           // [B,T,D]  4194304
  float* out1 = out + (size_t)NROWS * D_;      // [B,D,T]  4194304
  float* out2 = out + 2 * (size_t)NROWS * D_;  // [B,T]    32768 (as float)

  float* wsq = (float*)d_ws;                              // 16 KB
  int*   q   = (int*)((char*)d_ws + K_ * sizeof(float));  // 128 KB
  size_t base = K_ * sizeof(float) + NROWS * sizeof(int);
  // Wtb (2 MB + 16 KB prefetch slack): workspace if it fits, else stash in out0
  // (argmin reads it, scatter0 overwrites it afterwards — stream-ordered).
  float* Wtb = (ws_size >= base + (size_t)K_ * D_ * sizeof(float) + 16384)
                   ? (float*)((char*)d_ws + base)
                   : out0;

  wsq_kernel<<<K_ / 256, 256, 0, stream>>>(W, wsq);
  {
    dim3 g(K_ / 32, D_ / 32);
    transpose_kernel<<<g, 256, 0, stream>>>(W, Wtb);
  }
  argmin_kernel<<<NROWS / BM, 512, 0, stream>>>(x, Wtb, wsq, q, out2);
  scatter0_kernel<<<NROWS / 2, 256, 0, stream>>>(W, q, out0);
  scatter1_kernel<<<B_ * D_, 256, 0, stream>>>(W, q, out1);
}